// Round 9
// baseline (279.400 us; speedup 1.0000x reference)
//
#include <hip/hip_runtime.h>
#include <hip/hip_bf16.h>

#define NB 16
#define VV 5000
#define NFD 352
#define KD 120
#define NCH 5
#define SLABSZ (352 * 120)

typedef __attribute__((ext_vector_type(8))) short short8;
typedef __attribute__((ext_vector_type(4))) float float4v;

__device__ __forceinline__ unsigned short bfb(float a) {
    return __builtin_bit_cast(unsigned short, __float2bfloat16(a));
}

// split fp32 -> bf16 hi + bf16 lo(residual), pack 8 of each into int4
__device__ __forceinline__ void pack8(const float* f, int4& hi, int4& lo) {
    unsigned short h[8], l[8];
    #pragma unroll
    for (int j = 0; j < 8; ++j) {
        const float a = f[j];
        const __hip_bfloat16 hb = __float2bfloat16(a);
        h[j] = __builtin_bit_cast(unsigned short, hb);
        l[j] = bfb(a - __bfloat162float(hb));
    }
    hi.x = h[0] | (h[1] << 16); hi.y = h[2] | (h[3] << 16);
    hi.z = h[4] | (h[5] << 16); hi.w = h[6] | (h[7] << 16);
    lo.x = l[0] | (l[1] << 16); lo.y = l[2] | (l[3] << 16);
    lo.z = l[4] | (l[5] << 16); lo.w = l[6] | (l[7] << 16);
}

// ---------------------------------------------------------------------------
// proj v4: F_hat[b,f,k] = sum_v feat[b,v,f]*evecs[b,v,k]
// NO LDS, NO BARRIERS. v3 was latency-bound (9000 cyc/step vs ~1500 of real
// work; MfmaUtil/VALUBusy/HBM all <20%): the global->reg->pack->ds_write->
// barrier->ds_read round trip serialized each step across 8 barrier-locked
// waves/CU. Here each lane loads its MFMA fragment elements DIRECTLY from
// global (fa[mf][j] = A[(v0+8g+j)*NFD + m], coalesced 64B per 16-lane group),
// packs to bf16 hi/lo in-register, feeds MFMA. P/Q register double-buffer,
// 1-step prefetch, waves fully independent. Cost: A,B each fetched 2x per
// block (2 waves share) — L1/L2 absorb it.
// Tile 128x128 per block (4 waves as 2x2, wave tile 64x64), BK=32.
// grid (15,2,16) with bijective XCD swizzle; ch-chunks: 4x1024 + 904.
// ---------------------------------------------------------------------------
__global__ __launch_bounds__(256, 2) void proj_mfma(
    const float* __restrict__ fx, const float* __restrict__ fy,
    const float* __restrict__ ex, const float* __restrict__ ey,
    float* __restrict__ partials)
{
    const int t = threadIdx.x;

    // ---- bijective XCD-chunk swizzle: 480 blocks = 8 XCDs x 60 ----
    int lin = blockIdx.x + 15 * (blockIdx.y + 2 * blockIdx.z);
    lin = (lin & 7) * 60 + (lin >> 3);
    const int xx   = lin % 15;
    const int rest = lin / 15;
    const int wh = rest & 1;
    const int b  = rest >> 1;
    const int mt = xx % 3;
    const int ch = xx / 3;

    const float* Ab = (wh ? fy : fx) + (size_t)b * VV * NFD;
    const float* Bb = (wh ? ey : ex) + (size_t)b * VV * KD;
    const int m0 = mt * 128;

    // ---- wave geometry: 4 waves as 2x2, wave tile 64x64 ----
    const int lane = t & 63;
    const int wid  = t >> 6;
    const int wm = wid >> 1, wn = wid & 1;
    const int r16 = lane & 15;
    const int g   = lane >> 4;          // k-octet of this lane
    const int vbase = g * 8;

    int acolw[4], bcolw[4];
    #pragma unroll
    for (int mf = 0; mf < 4; ++mf)
        acolw[mf] = min(m0 + wm * 64 + mf * 16 + r16, NFD - 1);  // clamp; dup rows masked at C-write
    #pragma unroll
    for (int nf = 0; nf < 4; ++nf)
        bcolw[nf] = min(wn * 64 + nf * 16 + r16, KD - 1);

    float4v acc[4][4];
    #pragma unroll
    for (int mf = 0; mf < 4; ++mf)
        #pragma unroll
        for (int nf = 0; nf < 4; ++nf)
            acc[mf][nf] = float4v{0.f, 0.f, 0.f, 0.f};

    const int chv0 = ch * 1024;
    const int nst  = (ch < 4) ? 32 : 29;   // 4*1024 + 29*32(tail 8) >= 5000
    const bool lastch = (ch == 4);

    float faP[4][8], fbP[4][8], faQ[4][8], fbQ[4][8];

    auto do_load = [&](float (&fa)[4][8], float (&fb)[4][8], int st, bool tail) {
        const int v0 = chv0 + st * 32 + vbase;     // lane-specific
        const float* pa = Ab + (size_t)v0 * NFD;
        const float* pb = Bb + (size_t)v0 * KD;
        if (!tail) {
            #pragma unroll
            for (int mf = 0; mf < 4; ++mf)
                #pragma unroll
                for (int j = 0; j < 8; ++j)
                    fa[mf][j] = pa[j * NFD + acolw[mf]];
            #pragma unroll
            for (int nf = 0; nf < 4; ++nf)
                #pragma unroll
                for (int j = 0; j < 8; ++j)
                    fb[nf][j] = pb[j * KD + bcolw[nf]];
        } else {
            #pragma unroll
            for (int j = 0; j < 8; ++j) {
                const bool ok = (v0 + j) < VV;     // exec-mask predication, no OOB access
                #pragma unroll
                for (int mf = 0; mf < 4; ++mf) {
                    float v = 0.f;
                    if (ok) v = pa[j * NFD + acolw[mf]];
                    fa[mf][j] = v;
                }
                #pragma unroll
                for (int nf = 0; nf < 4; ++nf) {
                    float v = 0.f;
                    if (ok) v = pb[j * KD + bcolw[nf]];
                    fb[nf][j] = v;
                }
            }
        }
    };

    auto do_compute = [&](float (&fa)[4][8], float (&fb)[4][8]) {
        short8 ah[4], al[4], bh[4], bl[4];
        #pragma unroll
        for (int mf = 0; mf < 4; ++mf) {
            int4 hi, lo;
            pack8(fa[mf], hi, lo);
            ah[mf] = __builtin_bit_cast(short8, hi);
            al[mf] = __builtin_bit_cast(short8, lo);
        }
        #pragma unroll
        for (int nf = 0; nf < 4; ++nf) {
            int4 hi, lo;
            pack8(fb[nf], hi, lo);
            bh[nf] = __builtin_bit_cast(short8, hi);
            bl[nf] = __builtin_bit_cast(short8, lo);
        }
        #pragma unroll
        for (int mf = 0; mf < 4; ++mf)
            #pragma unroll
            for (int nf = 0; nf < 4; ++nf) {
                acc[mf][nf] = __builtin_amdgcn_mfma_f32_16x16x32_bf16(ah[mf], bh[nf], acc[mf][nf], 0, 0, 0);
                acc[mf][nf] = __builtin_amdgcn_mfma_f32_16x16x32_bf16(ah[mf], bl[nf], acc[mf][nf], 0, 0, 0);
                acc[mf][nf] = __builtin_amdgcn_mfma_f32_16x16x32_bf16(al[mf], bh[nf], acc[mf][nf], 0, 0, 0);
            }
    };

    // ---- software-pipelined, barrier-free main loop ----
    do_load(faP, fbP, 0, lastch && (nst == 1));
    for (int st = 0; st < nst; st += 2) {
        if (st + 1 < nst) do_load(faQ, fbQ, st + 1, lastch && (st + 1 == nst - 1));
        do_compute(faP, fbP);
        if (st + 1 >= nst) break;
        if (st + 2 < nst) do_load(faP, fbP, st + 2, lastch && (st + 2 == nst - 1));
        do_compute(faQ, fbQ);
    }

    // ---- store partial C tile: slab[m*120 + n] ----
    float* slab = partials + (size_t)((ch * 2 + wh) * NB + b) * SLABSZ;
    #pragma unroll
    for (int mf = 0; mf < 4; ++mf) {
        const int mrow = mt * 128 + wm * 64 + mf * 16 + g * 4;
        #pragma unroll
        for (int nf = 0; nf < 4; ++nf) {
            const int n = wn * 64 + nf * 16 + r16;
            if (n < KD) {
                #pragma unroll
                for (int r = 0; r < 4; ++r) {
                    const int m = mrow + r;
                    if (m < NFD) slab[(size_t)m * KD + n] = acc[mf][nf][r];
                }
            }
        }
    }
}

// ---------------------------------------------------------------------------
// reduce (unchanged)
// ---------------------------------------------------------------------------
__global__ __launch_bounds__(256) void reduce_k(
    const float* __restrict__ partials, float* __restrict__ fhat, float* __restrict__ ghat)
{
    const int id = blockIdx.x * 256 + threadIdx.x;
    if (id >= NFD * KD) return;
    const int wb = blockIdx.y;
    const int wh = wb >> 4;
    const int b  = wb & 15;

    const float* p = partials + (size_t)(wh * NB + b) * SLABSZ + id;
    const size_t chstride = (size_t)2 * NB * SLABSZ;

    float s = 0.f;
    #pragma unroll
    for (int c = 0; c < NCH; ++c) s += p[c * chstride];

    float* dst = (wh ? ghat : fhat) + (size_t)b * NFD * KD + id;
    *dst = s;
}

// ---------------------------------------------------------------------------
// Generic TN SGEMM 64x64 tile — used by gram (unchanged, passing).
// ---------------------------------------------------------------------------
__device__ __forceinline__ void gemm_tn_64x64(
    const float* __restrict__ A, const float* __restrict__ B, float* __restrict__ C,
    int V, int M, int N, int m0, int n0)
{
    __shared__ float As[16][64];
    __shared__ float Bs[16][64];

    const int tid = threadIdx.x;
    const int tx = tid & 15;
    const int ty = tid >> 4;
    const int sr = tid >> 4;
    const int sc = (tid & 15) << 2;

    float acc[4][4] = {{0.f,0.f,0.f,0.f},{0.f,0.f,0.f,0.f},
                       {0.f,0.f,0.f,0.f},{0.f,0.f,0.f,0.f}};

    for (int v0 = 0; v0 < V; v0 += 16) {
        const int v = v0 + sr;
        float4 av; av.x = av.y = av.z = av.w = 0.f;
        float4 bv; bv.x = bv.y = bv.z = bv.w = 0.f;
        if (v < V) {
            const float* Ar = A + (size_t)v * M;
            const int ca = m0 + sc;
            if (ca + 3 < M) {
                av = *(const float4*)(Ar + ca);
            } else {
                if (ca + 0 < M) av.x = Ar[ca + 0];
                if (ca + 1 < M) av.y = Ar[ca + 1];
                if (ca + 2 < M) av.z = Ar[ca + 2];
                if (ca + 3 < M) av.w = Ar[ca + 3];
            }
            const float* Br = B + (size_t)v * N;
            const int cb = n0 + sc;
            if (cb + 3 < N) {
                bv = *(const float4*)(Br + cb);
            } else {
                if (cb + 0 < N) bv.x = Br[cb + 0];
                if (cb + 1 < N) bv.y = Br[cb + 1];
                if (cb + 2 < N) bv.z = Br[cb + 2];
                if (cb + 3 < N) bv.w = Br[cb + 3];
            }
        }
        __syncthreads();
        *(float4*)&As[sr][sc] = av;
        *(float4*)&Bs[sr][sc] = bv;
        __syncthreads();

        #pragma unroll
        for (int kk = 0; kk < 16; ++kk) {
            const float4 a4 = *(const float4*)&As[kk][ty << 2];
            const float4 b4 = *(const float4*)&Bs[kk][tx << 2];
            const float a[4]  = {a4.x, a4.y, a4.z, a4.w};
            const float bb[4] = {b4.x, b4.y, b4.z, b4.w};
            #pragma unroll
            for (int i = 0; i < 4; ++i)
                #pragma unroll
                for (int j = 0; j < 4; ++j)
                    acc[i][j] = fmaf(a[i], bb[j], acc[i][j]);
        }
    }

    #pragma unroll
    for (int i = 0; i < 4; ++i) {
        const int m = m0 + (ty << 2) + i;
        if (m < M) {
            #pragma unroll
            for (int j = 0; j < 4; ++j) {
                const int n = n0 + (tx << 2) + j;
                if (n < N) C[(size_t)m * N + n] = acc[i][j];
            }
        }
    }
}

__global__ __launch_bounds__(256) void gram_kernel(
    const float* __restrict__ fhat, const float* __restrict__ ghat,
    float* __restrict__ ftf, float* __restrict__ gtg, float* __restrict__ ftg)
{
    const int b = blockIdx.z;
    const int which = blockIdx.y;
    const int m0 = (blockIdx.x & 1) * 64;
    const int n0 = (blockIdx.x >> 1) * 64;

    const float* F = fhat + (size_t)b * NFD * KD;
    const float* G = ghat + (size_t)b * NFD * KD;
    const float* A  = (which == 1) ? G : F;
    const float* Bp = (which == 0) ? F : G;
    float* C = ((which == 0) ? ftf : (which == 1) ? gtg : ftg) + (size_t)b * KD * KD;

    gemm_tn_64x64(A, Bp, C, NFD, KD, KD, m0, n0);
}

// ---------------------------------------------------------------------------
// solve v6 (unchanged, passing): 480-thread Gauss-Jordan, 60 named scalars,
// padded 20-float prow segments (bank-clean), R=4 row reuse.
// ---------------------------------------------------------------------------
__device__ __forceinline__ float ldval(const float* __restrict__ A, const float* __restrict__ B,
                                       int pair, int row, int col) {
    if (col < KD) return A[row * KD + col];
    const int l = col - KD;
    return pair ? B[l * KD + row] : B[row * KD + l];
}

#define FOR15(OP) OP(0) OP(1) OP(2) OP(3) OP(4) OP(5) OP(6) OP(7) OP(8) OP(9) \
                  OP(10) OP(11) OP(12) OP(13) OP(14)

__global__ __launch_bounds__(480, 1) void solve_kernel(
    const float* __restrict__ ftf, const float* __restrict__ gtg,
    const float* __restrict__ ftg, float* __restrict__ out)
{
    const int pair = blockIdx.x;
    const int b = blockIdx.y;
    const int tid = threadIdx.x;
    const int cg = tid & 15;
    const int rg = tid >> 4;
    const int cbase = cg * 15;
    const int r0 = rg * 4;
    const int seg = cg * 20;

    const float* Ag = ((pair == 0) ? ftf : gtg) + (size_t)b * KD * KD;
    const float* Bg = ftg + (size_t)b * KD * KD;

    __shared__ __align__(16) float prow[2][320];
    __shared__ __align__(16) float pcol[2][120];

    #define DECL(I) float w##I = ldval(Ag, Bg, pair, r0 + 0, cbase + (I)); \
                    float x##I = ldval(Ag, Bg, pair, r0 + 1, cbase + (I)); \
                    float y##I = ldval(Ag, Bg, pair, r0 + 2, cbase + (I)); \
                    float z##I = ldval(Ag, Bg, pair, r0 + 3, cbase + (I));
    FOR15(DECL)
    #undef DECL

    if (rg == 0) {
        #define PUB0(I) prow[0][seg + (I)] = w##I;
        FOR15(PUB0)
        #undef PUB0
    }
    if (cg == 0) *(float4*)&pcol[0][r0] = float4{w0, x0, y0, z0};
    __syncthreads();

    int jseg = 0, joff = 0;

    for (int j = 0; j < KD; ++j) {
        const int cur = j & 1;
        const int nxt = cur ^ 1;

        const float pinv = 1.0f / prow[cur][jseg * 20 + joff];
        const float4 f4 = *(const float4*)&pcol[cur][r0];

        const float4 q0 = *(const float4*)&prow[cur][seg + 0];
        const float4 q1 = *(const float4*)&prow[cur][seg + 4];
        const float4 q2 = *(const float4*)&prow[cur][seg + 8];
        const float4 q3 = *(const float4*)&prow[cur][seg + 12];
        const float p0 = q0.x, p1 = q0.y, p2 = q0.z, p3 = q0.w;
        const float p4 = q1.x, p5 = q1.y, p6 = q1.z, p7 = q1.w;
        const float p8 = q2.x, p9 = q2.y, p10 = q2.z, p11 = q2.w;
        const float p12 = q3.x, p13 = q3.y, p14 = q3.z;

        const float fw = f4.x * pinv, fx = f4.y * pinv;
        const float fy = f4.z * pinv, fz = f4.w * pinv;

        #define UPD(I) w##I = fmaf(-fw, p##I, w##I); x##I = fmaf(-fx, p##I, x##I); \
                       y##I = fmaf(-fy, p##I, y##I); z##I = fmaf(-fz, p##I, z##I);
        FOR15(UPD)
        #undef UPD

        if (rg == (j >> 2)) {
            #define FW(I) w##I = p##I * pinv;
            #define FX(I) x##I = p##I * pinv;
            #define FY(I) y##I = p##I * pinv;
            #define FZ(I) z##I = p##I * pinv;
            switch (j & 3) {
                case 0: FOR15(FW) break;
                case 1: FOR15(FX) break;
                case 2: FOR15(FY) break;
                default: FOR15(FZ) break;
            }
            #undef FW
            #undef FX
            #undef FY
            #undef FZ
        }

        const int j2 = j + 1;

        if (j2 < KD && rg == (j2 >> 2)) {
            #define PW(I) prow[nxt][seg + (I)] = w##I;
            #define PX(I) prow[nxt][seg + (I)] = x##I;
            #define PY(I) prow[nxt][seg + (I)] = y##I;
            #define PZ(I) prow[nxt][seg + (I)] = z##I;
            switch (j2 & 3) {
                case 0: FOR15(PW) break;
                case 1: FOR15(PX) break;
                case 2: FOR15(PY) break;
                default: FOR15(PZ) break;
            }
            #undef PW
            #undef PX
            #undef PY
            #undef PZ
        }

        joff++; if (joff == 15) { joff = 0; jseg++; }
        if (j2 < KD && cg == jseg) {
            #define PC(I) case I: *(float4*)&pcol[nxt][r0] = float4{w##I, x##I, y##I, z##I}; break;
            switch (joff) {
                FOR15(PC)
                default: break;
            }
            #undef PC
        }
        __syncthreads();
    }

    if (cg >= 8) {
        float* op = out + (size_t)pair * NB * KD * KD + (size_t)b * KD * KD;
        #define OUTW(I) { const int l = cbase + (I) - KD; \
                          *(float4*)&op[l * KD + r0] = float4{w##I, x##I, y##I, z##I}; }
        FOR15(OUTW)
        #undef OUTW
    }
}

// ---------------------------------------------------------------------------
extern "C" void kernel_launch(void* const* d_in, const int* in_sizes, int n_in,
                              void* d_out, int out_size, void* d_ws, size_t ws_size,
                              hipStream_t stream)
{
    const float* feat_x  = (const float*)d_in[0];
    const float* feat_y  = (const float*)d_in[1];
    const float* evecs_x = (const float*)d_in[2];
    const float* evecs_y = (const float*)d_in[3];
    float* out = (float*)d_out;

    float* ws       = (float*)d_ws;
    float* partials = ws;
    float* fhat     = partials + (size_t)NCH * 2 * NB * SLABSZ;
    float* ghat     = fhat + (size_t)NB * NFD * KD;
    float* ftf      = ws;                                 // aliases partials (dead after reduce)
    float* gtg      = ftf + (size_t)NB * KD * KD;
    float* ftg      = gtg + (size_t)NB * KD * KD;

    proj_mfma <<<dim3(15, 2, NB), 256, 0, stream>>>(feat_x, feat_y, evecs_x, evecs_y, partials);
    reduce_k  <<<dim3(165, 32), 256, 0, stream>>>(partials, fhat, ghat);
    gram_kernel<<<dim3(4, 3, NB), 256, 0, stream>>>(fhat, ghat, ftf, gtg, ftg);
    solve_kernel<<<dim3(2, NB), 480, 0, stream>>>(ftf, gtg, ftg, out);
}

// Round 10
// 247.360 us; speedup vs baseline: 1.1295x; 1.1295x over previous
//
#include <hip/hip_runtime.h>
#include <hip/hip_bf16.h>

#define NB 16
#define VV 5000
#define NFD 352
#define KD 120
#define NCH 5
#define SLABSZ (352 * 120)

typedef __attribute__((ext_vector_type(8))) short short8;
typedef __attribute__((ext_vector_type(4))) float float4v;

__device__ __forceinline__ void load_lds16(const float* g, float* l) {
    __builtin_amdgcn_global_load_lds(
        (const __attribute__((address_space(1))) unsigned int*)g,
        (__attribute__((address_space(3))) unsigned int*)l, 16, 0, 0);
}

__device__ __forceinline__ unsigned short bfb(float a) {
    return __builtin_bit_cast(unsigned short, __float2bfloat16(a));
}

// split fp32 -> bf16 hi + bf16 lo(residual), pack 8 of each into int4
__device__ __forceinline__ void pack8(const float* f, int4& hi, int4& lo) {
    unsigned short h[8], l[8];
    #pragma unroll
    for (int j = 0; j < 8; ++j) {
        const float a = f[j];
        const __hip_bfloat16 hb = __float2bfloat16(a);
        h[j] = __builtin_bit_cast(unsigned short, hb);
        l[j] = bfb(a - __bfloat162float(hb));
    }
    hi.x = h[0] | (h[1] << 16); hi.y = h[2] | (h[3] << 16);
    hi.z = h[4] | (h[5] << 16); hi.w = h[6] | (h[7] << 16);
    lo.x = l[0] | (l[1] << 16); lo.y = l[2] | (l[3] << 16);
    lo.z = l[4] | (l[5] << 16); lo.w = l[6] | (l[7] << 16);
}

// read 8 k-strided fp32 from swizzled [v][*] LDS plane, convert to bf16 hi/lo
template <int RS>
__device__ __forceinline__ void frag_from_lds(const float* base, int col, int g,
                                              short8& hi8, short8& lo8) {
    float f[8];
    #pragma unroll
    for (int j = 0; j < 8; ++j) {
        const int v = g * 8 + j;
        f[j] = base[v * RS + (((col >> 2) ^ (v & 7)) << 2) + (col & 3)];
    }
    int4 hi, lo;
    pack8(f, hi, lo);
    hi8 = __builtin_bit_cast(short8, hi);
    lo8 = __builtin_bit_cast(short8, lo);
}

// ---------------------------------------------------------------------------
// proj v5: F_hat[b,f,k] = sum_v feat[b,v,f]*evecs[b,v,k]
// v4 spilled (reg dbuf needs ~280 VGPR; WRITE_SIZE 146MB scratch). v2/v3 were
// grid-limited (480 blk x 4 waves / 256 CU = 7.5 waves/CU -> latency-bound).
// v5: tile 64x128, BK=32, 960 blocks (6mt x 5ch x 2 x 16) ~= 15 waves/CU;
// fp32 staged by global_load_lds (0 VGPR, 0 VALU staging); bf16 hi/lo
// conversion at fragment read (2x redundant, ~7us total). LDS 24KB single
// buffer: A[32v][64m] + B[32v][128n], XOR-swizzled groups (phys grp =
// (c>>2)^(v&7)); gload_lds dest linear, source pre-inverse-swizzled (both-
// sides rule). acc 2x4 frags = 32 VGPR; launch_bounds(256,4) caps 128.
// ---------------------------------------------------------------------------
__global__ __launch_bounds__(256, 4) void proj_mfma(
    const float* __restrict__ fx, const float* __restrict__ fy,
    const float* __restrict__ ex, const float* __restrict__ ey,
    float* __restrict__ partials, const float* __restrict__ zeropad)
{
    const int t = threadIdx.x;

    // bijective XCD swizzle: 960 = 8 x 120; consecutive lin2 (= same XCD)
    // walk mt fastest -> 6 mt sharing one B panel co-locate on an XCD L2.
    int lin = blockIdx.x + 30 * (blockIdx.y + 2 * blockIdx.z);
    lin = (lin & 7) * 120 + (lin >> 3);
    const int xx   = lin % 30;
    const int rest = lin / 30;
    const int wh = rest & 1;
    const int b  = rest >> 1;
    const int mt = xx % 6;
    const int ch = xx / 6;

    const float* Ab = (wh ? fy : fx) + (size_t)b * VV * NFD;
    const float* Bb = (wh ? ey : ex) + (size_t)b * VV * KD;
    const int m0 = mt * 64;

    __shared__ float lds[6144];   // A: [0,2048) = 32x64 ; B: [2048,6144) = 32x128

    // ---- staging precompute (A: 2 units, B: 4 units of 16B per thread) ----
    const float* aSrc[2]; int av[2];
    #pragma unroll
    for (int i = 0; i < 2; ++i) {
        const int u = i * 256 + t;          // 0..511
        const int v = u >> 4;               // 0..31
        const int gg = u & 15;
        const int lg = gg ^ (v & 7);        // logical m-group (inverse swizzle)
        const int col = min(m0 + lg * 4, NFD - 4);   // clamp: garbage masked at C-write
        aSrc[i] = Ab + col;
        av[i] = v;
    }
    const float* bSrc[4]; int bv[4]; bool bok[4];
    #pragma unroll
    for (int i = 0; i < 4; ++i) {
        const int u = i * 256 + t;          // 0..1023
        const int v = u >> 5;               // 0..31
        const int gg = u & 31;
        const int lg = gg ^ (v & 7);
        const int col = lg * 4;
        bok[i] = (col < KD);
        bSrc[i] = Bb + (bok[i] ? col : 0);
        bv[i] = v;
    }

    // ---- wave geometry: 4 waves 2x2, wave tile 32(m) x 64(n) ----
    const int lane = t & 63;
    const int wid  = t >> 6;
    const int wm = wid >> 1, wn = wid & 1;
    const int r16 = lane & 15;
    const int g   = lane >> 4;

    float4v acc[2][4];
    #pragma unroll
    for (int mf = 0; mf < 2; ++mf)
        #pragma unroll
        for (int nf = 0; nf < 4; ++nf)
            acc[mf][nf] = float4v{0.f, 0.f, 0.f, 0.f};

    const int chv0 = ch * 1024;
    const int nst  = (ch < 4) ? 32 : 29;    // ch4: 904 valid v, tail zeropadded

    for (int st = 0; st < nst; ++st) {
        const int v0 = chv0 + st * 32;

        #pragma unroll
        for (int i = 0; i < 2; ++i) {
            const int vg = v0 + av[i];
            const float* src = (vg < VV) ? (aSrc[i] + (size_t)vg * NFD) : zeropad;
            load_lds16(src, &lds[(i * 256 + t) * 4]);
        }
        #pragma unroll
        for (int i = 0; i < 4; ++i) {
            const int vg = v0 + bv[i];
            const float* src = (bok[i] && vg < VV) ? (bSrc[i] + (size_t)vg * KD) : zeropad;
            load_lds16(src, &lds[2048 + (i * 256 + t) * 4]);
        }
        __syncthreads();   // drains vmcnt (global_load_lds) + orders LDS

        short8 bh[4], bl[4];
        #pragma unroll
        for (int nf = 0; nf < 4; ++nf)
            frag_from_lds<128>(&lds[2048], wn * 64 + nf * 16 + r16, g, bh[nf], bl[nf]);

        #pragma unroll
        for (int mf = 0; mf < 2; ++mf) {
            short8 ah, al;
            frag_from_lds<64>(&lds[0], wm * 32 + mf * 16 + r16, g, ah, al);
            #pragma unroll
            for (int nf = 0; nf < 4; ++nf) {
                acc[mf][nf] = __builtin_amdgcn_mfma_f32_16x16x32_bf16(ah, bh[nf], acc[mf][nf], 0, 0, 0);
                acc[mf][nf] = __builtin_amdgcn_mfma_f32_16x16x32_bf16(ah, bl[nf], acc[mf][nf], 0, 0, 0);
                acc[mf][nf] = __builtin_amdgcn_mfma_f32_16x16x32_bf16(al, bh[nf], acc[mf][nf], 0, 0, 0);
            }
        }
        __syncthreads();
    }

    // ---- store partial C tile: slab[m*120 + n] ----
    float* slab = partials + (size_t)((ch * 2 + wh) * NB + b) * SLABSZ;
    #pragma unroll
    for (int mf = 0; mf < 2; ++mf) {
        const int mrow = mt * 64 + wm * 32 + mf * 16 + g * 4;
        #pragma unroll
        for (int nf = 0; nf < 4; ++nf) {
            const int n = wn * 64 + nf * 16 + r16;
            if (n < KD) {
                #pragma unroll
                for (int r = 0; r < 4; ++r) {
                    const int m = mrow + r;
                    if (m < NFD) slab[(size_t)m * KD + n] = acc[mf][nf][r];
                }
            }
        }
    }
}

// ---------------------------------------------------------------------------
// reduce (unchanged)
// ---------------------------------------------------------------------------
__global__ __launch_bounds__(256) void reduce_k(
    const float* __restrict__ partials, float* __restrict__ fhat, float* __restrict__ ghat)
{
    const int id = blockIdx.x * 256 + threadIdx.x;
    if (id >= NFD * KD) return;
    const int wb = blockIdx.y;
    const int wh = wb >> 4;
    const int b  = wb & 15;

    const float* p = partials + (size_t)(wh * NB + b) * SLABSZ + id;
    const size_t chstride = (size_t)2 * NB * SLABSZ;

    float s = 0.f;
    #pragma unroll
    for (int c = 0; c < NCH; ++c) s += p[c * chstride];

    float* dst = (wh ? ghat : fhat) + (size_t)b * NFD * KD + id;
    *dst = s;
}

// ---------------------------------------------------------------------------
// Generic TN SGEMM 64x64 tile — used by gram (unchanged, passing).
// ---------------------------------------------------------------------------
__device__ __forceinline__ void gemm_tn_64x64(
    const float* __restrict__ A, const float* __restrict__ B, float* __restrict__ C,
    int V, int M, int N, int m0, int n0)
{
    __shared__ float As[16][64];
    __shared__ float Bs[16][64];

    const int tid = threadIdx.x;
    const int tx = tid & 15;
    const int ty = tid >> 4;
    const int sr = tid >> 4;
    const int sc = (tid & 15) << 2;

    float acc[4][4] = {{0.f,0.f,0.f,0.f},{0.f,0.f,0.f,0.f},
                       {0.f,0.f,0.f,0.f},{0.f,0.f,0.f,0.f}};

    for (int v0 = 0; v0 < V; v0 += 16) {
        const int v = v0 + sr;
        float4 av; av.x = av.y = av.z = av.w = 0.f;
        float4 bv; bv.x = bv.y = bv.z = bv.w = 0.f;
        if (v < V) {
            const float* Ar = A + (size_t)v * M;
            const int ca = m0 + sc;
            if (ca + 3 < M) {
                av = *(const float4*)(Ar + ca);
            } else {
                if (ca + 0 < M) av.x = Ar[ca + 0];
                if (ca + 1 < M) av.y = Ar[ca + 1];
                if (ca + 2 < M) av.z = Ar[ca + 2];
                if (ca + 3 < M) av.w = Ar[ca + 3];
            }
            const float* Br = B + (size_t)v * N;
            const int cb = n0 + sc;
            if (cb + 3 < N) {
                bv = *(const float4*)(Br + cb);
            } else {
                if (cb + 0 < N) bv.x = Br[cb + 0];
                if (cb + 1 < N) bv.y = Br[cb + 1];
                if (cb + 2 < N) bv.z = Br[cb + 2];
                if (cb + 3 < N) bv.w = Br[cb + 3];
            }
        }
        __syncthreads();
        *(float4*)&As[sr][sc] = av;
        *(float4*)&Bs[sr][sc] = bv;
        __syncthreads();

        #pragma unroll
        for (int kk = 0; kk < 16; ++kk) {
            const float4 a4 = *(const float4*)&As[kk][ty << 2];
            const float4 b4 = *(const float4*)&Bs[kk][tx << 2];
            const float a[4]  = {a4.x, a4.y, a4.z, a4.w};
            const float bb[4] = {b4.x, b4.y, b4.z, b4.w};
            #pragma unroll
            for (int i = 0; i < 4; ++i)
                #pragma unroll
                for (int j = 0; j < 4; ++j)
                    acc[i][j] = fmaf(a[i], bb[j], acc[i][j]);
        }
    }

    #pragma unroll
    for (int i = 0; i < 4; ++i) {
        const int m = m0 + (ty << 2) + i;
        if (m < M) {
            #pragma unroll
            for (int j = 0; j < 4; ++j) {
                const int n = n0 + (tx << 2) + j;
                if (n < N) C[(size_t)m * N + n] = acc[i][j];
            }
        }
    }
}

__global__ __launch_bounds__(256) void gram_kernel(
    const float* __restrict__ fhat, const float* __restrict__ ghat,
    float* __restrict__ ftf, float* __restrict__ gtg, float* __restrict__ ftg)
{
    const int b = blockIdx.z;
    const int which = blockIdx.y;
    const int m0 = (blockIdx.x & 1) * 64;
    const int n0 = (blockIdx.x >> 1) * 64;

    const float* F = fhat + (size_t)b * NFD * KD;
    const float* G = ghat + (size_t)b * NFD * KD;
    const float* A  = (which == 1) ? G : F;
    const float* Bp = (which == 0) ? F : G;
    float* C = ((which == 0) ? ftf : (which == 1) ? gtg : ftg) + (size_t)b * KD * KD;

    gemm_tn_64x64(A, Bp, C, NFD, KD, KD, m0, n0);
}

// ---------------------------------------------------------------------------
// solve v6 (unchanged, passing): 480-thread Gauss-Jordan, 60 named scalars,
// padded 20-float prow segments (bank-clean), R=4 row reuse.
// ---------------------------------------------------------------------------
__device__ __forceinline__ float ldval(const float* __restrict__ A, const float* __restrict__ B,
                                       int pair, int row, int col) {
    if (col < KD) return A[row * KD + col];
    const int l = col - KD;
    return pair ? B[l * KD + row] : B[row * KD + l];
}

#define FOR15(OP) OP(0) OP(1) OP(2) OP(3) OP(4) OP(5) OP(6) OP(7) OP(8) OP(9) \
                  OP(10) OP(11) OP(12) OP(13) OP(14)

__global__ __launch_bounds__(480, 1) void solve_kernel(
    const float* __restrict__ ftf, const float* __restrict__ gtg,
    const float* __restrict__ ftg, float* __restrict__ out)
{
    const int pair = blockIdx.x;
    const int b = blockIdx.y;
    const int tid = threadIdx.x;
    const int cg = tid & 15;
    const int rg = tid >> 4;
    const int cbase = cg * 15;
    const int r0 = rg * 4;
    const int seg = cg * 20;

    const float* Ag = ((pair == 0) ? ftf : gtg) + (size_t)b * KD * KD;
    const float* Bg = ftg + (size_t)b * KD * KD;

    __shared__ __align__(16) float prow[2][320];
    __shared__ __align__(16) float pcol[2][120];

    #define DECL(I) float w##I = ldval(Ag, Bg, pair, r0 + 0, cbase + (I)); \
                    float x##I = ldval(Ag, Bg, pair, r0 + 1, cbase + (I)); \
                    float y##I = ldval(Ag, Bg, pair, r0 + 2, cbase + (I)); \
                    float z##I = ldval(Ag, Bg, pair, r0 + 3, cbase + (I));
    FOR15(DECL)
    #undef DECL

    if (rg == 0) {
        #define PUB0(I) prow[0][seg + (I)] = w##I;
        FOR15(PUB0)
        #undef PUB0
    }
    if (cg == 0) *(float4*)&pcol[0][r0] = float4{w0, x0, y0, z0};
    __syncthreads();

    int jseg = 0, joff = 0;

    for (int j = 0; j < KD; ++j) {
        const int cur = j & 1;
        const int nxt = cur ^ 1;

        const float pinv = 1.0f / prow[cur][jseg * 20 + joff];
        const float4 f4 = *(const float4*)&pcol[cur][r0];

        const float4 q0 = *(const float4*)&prow[cur][seg + 0];
        const float4 q1 = *(const float4*)&prow[cur][seg + 4];
        const float4 q2 = *(const float4*)&prow[cur][seg + 8];
        const float4 q3 = *(const float4*)&prow[cur][seg + 12];
        const float p0 = q0.x, p1 = q0.y, p2 = q0.z, p3 = q0.w;
        const float p4 = q1.x, p5 = q1.y, p6 = q1.z, p7 = q1.w;
        const float p8 = q2.x, p9 = q2.y, p10 = q2.z, p11 = q2.w;
        const float p12 = q3.x, p13 = q3.y, p14 = q3.z;

        const float fw = f4.x * pinv, fx = f4.y * pinv;
        const float fy = f4.z * pinv, fz = f4.w * pinv;

        #define UPD(I) w##I = fmaf(-fw, p##I, w##I); x##I = fmaf(-fx, p##I, x##I); \
                       y##I = fmaf(-fy, p##I, y##I); z##I = fmaf(-fz, p##I, z##I);
        FOR15(UPD)
        #undef UPD

        if (rg == (j >> 2)) {
            #define FW(I) w##I = p##I * pinv;
            #define FX(I) x##I = p##I * pinv;
            #define FY(I) y##I = p##I * pinv;
            #define FZ(I) z##I = p##I * pinv;
            switch (j & 3) {
                case 0: FOR15(FW) break;
                case 1: FOR15(FX) break;
                case 2: FOR15(FY) break;
                default: FOR15(FZ) break;
            }
            #undef FW
            #undef FX
            #undef FY
            #undef FZ
        }

        const int j2 = j + 1;

        if (j2 < KD && rg == (j2 >> 2)) {
            #define PW(I) prow[nxt][seg + (I)] = w##I;
            #define PX(I) prow[nxt][seg + (I)] = x##I;
            #define PY(I) prow[nxt][seg + (I)] = y##I;
            #define PZ(I) prow[nxt][seg + (I)] = z##I;
            switch (j2 & 3) {
                case 0: FOR15(PW) break;
                case 1: FOR15(PX) break;
                case 2: FOR15(PY) break;
                default: FOR15(PZ) break;
            }
            #undef PW
            #undef PX
            #undef PY
            #undef PZ
        }

        joff++; if (joff == 15) { joff = 0; jseg++; }
        if (j2 < KD && cg == jseg) {
            #define PC(I) case I: *(float4*)&pcol[nxt][r0] = float4{w##I, x##I, y##I, z##I}; break;
            switch (joff) {
                FOR15(PC)
                default: break;
            }
            #undef PC
        }
        __syncthreads();
    }

    if (cg >= 8) {
        float* op = out + (size_t)pair * NB * KD * KD + (size_t)b * KD * KD;
        #define OUTW(I) { const int l = cbase + (I) - KD; \
                          *(float4*)&op[l * KD + r0] = float4{w##I, x##I, y##I, z##I}; }
        FOR15(OUTW)
        #undef OUTW
    }
}

// ---------------------------------------------------------------------------
extern "C" void kernel_launch(void* const* d_in, const int* in_sizes, int n_in,
                              void* d_out, int out_size, void* d_ws, size_t ws_size,
                              hipStream_t stream)
{
    const float* feat_x  = (const float*)d_in[0];
    const float* feat_y  = (const float*)d_in[1];
    const float* evecs_x = (const float*)d_in[2];
    const float* evecs_y = (const float*)d_in[3];
    float* out = (float*)d_out;

    // ws layout (floats): zeropad 64 | partials 6,758,400 | fhat/ghat 675,840 ea.
    // ftf/gtg/ftg alias the partials region (dead after reduce_k).
    float* ws       = (float*)d_ws;
    float* zeropad  = ws;
    float* partials = ws + 64;
    float* fhat     = partials + (size_t)NCH * 2 * NB * SLABSZ;
    float* ghat     = fhat + (size_t)NB * NFD * KD;
    float* ftf      = ws + 64;                            // aliases partials
    float* gtg      = ftf + (size_t)NB * KD * KD;
    float* ftg      = gtg + (size_t)NB * KD * KD;

    hipMemsetAsync(zeropad, 0, 256, stream);

    proj_mfma <<<dim3(30, 2, NB), 256, 0, stream>>>(feat_x, feat_y, evecs_x, evecs_y, partials, zeropad);
    reduce_k  <<<dim3(165, 32), 256, 0, stream>>>(partials, fhat, ghat);
    gram_kernel<<<dim3(4, 3, NB), 256, 0, stream>>>(fhat, ghat, ftf, gtg, ftg);
    solve_kernel<<<dim3(2, NB), 480, 0, stream>>>(ftf, gtg, ftg, out);
}

// Round 12
// 218.635 us; speedup vs baseline: 1.2779x; 1.1314x over previous
//
#include <hip/hip_runtime.h>
#include <hip/hip_bf16.h>

#define NB 16
#define VV 5000
#define NFD 352
#define KD 120
#define NCH 5
#define SLABSZ (352 * 120)

typedef __attribute__((ext_vector_type(8))) short short8;
typedef __attribute__((ext_vector_type(4))) float float4v;

__device__ __forceinline__ unsigned short bfb(float a) {
    return __builtin_bit_cast(unsigned short, __float2bfloat16(a));
}

// split fp32 -> bf16 hi + bf16 lo(residual), pack 8 of each into int4
__device__ __forceinline__ void pack8(const float* f, int4& hi, int4& lo) {
    unsigned short h[8], l[8];
    #pragma unroll
    for (int j = 0; j < 8; ++j) {
        const float a = f[j];
        const __hip_bfloat16 hb = __float2bfloat16(a);
        h[j] = __builtin_bit_cast(unsigned short, hb);
        l[j] = bfb(a - __bfloat162float(hb));
    }
    hi.x = h[0] | (h[1] << 16); hi.y = h[2] | (h[3] << 16);
    hi.z = h[4] | (h[5] << 16); hi.w = h[6] | (h[7] << 16);
    lo.x = l[0] | (l[1] << 16); lo.y = l[2] | (l[3] << 16);
    lo.z = l[4] | (l[5] << 16); lo.w = l[6] | (l[7] << 16);
}

// ---------------------------------------------------------------------------
// proj v6b: F_hat[b,f,k] = sum_v feat[b,v,f]*evecs[b,v,k]
// v6 with the stray pack_write line removed (it wrote B data at lds+bwb0,
// corrupting the A planes -> absmax 1.13).
// Structure: bf16 [m][k] planes, ONE ds_read_b128 per fragment, conversion
// once at staging; 30KB LDS, 960 blocks (~15 waves/CU); issue-early/
// write-late reg staging (T14). Bank-conflict-free via 80B-padded rows
// (bank-quad = 5m mod 8, bijective over m mod 8).
// LDS: A_hi[64 x 80B] @0 | A_lo @5120 | B_hi[128 x 80B] @10240 | B_lo @20480.
// Tile 64x128, BK=32, 4 waves 2x2 (wave tile 32x64), acc = 2x4 frags.
// grid (30,2,16) = 960 blocks, bijective XCD swizzle.
// ---------------------------------------------------------------------------
__global__ __launch_bounds__(256, 4) void proj_mfma(
    const float* __restrict__ fx, const float* __restrict__ fy,
    const float* __restrict__ ex, const float* __restrict__ ey,
    float* __restrict__ partials)
{
    const int t = threadIdx.x;

    // bijective XCD swizzle: 960 = 8 x 120; same-XCD neighbors walk mt fastest
    int lin = blockIdx.x + 30 * (blockIdx.y + 2 * blockIdx.z);
    lin = (lin & 7) * 120 + (lin >> 3);
    const int xx   = lin % 30;
    const int rest = lin / 30;
    const int wh = rest & 1;
    const int b  = rest >> 1;
    const int mt = xx % 6;
    const int ch = xx / 6;

    const float* Ab = (wh ? fy : fx) + (size_t)b * VV * NFD;
    const float* Bb = (wh ? ey : ex) + (size_t)b * VV * KD;
    const int m0 = mt * 64;

    __shared__ __align__(16) unsigned char lds[30720];

    // ---- staging geometry ----
    // A: 256 units = 64 m x 4 octets: m = t&63, o = t>>6
    const int am = t & 63;
    const int ao = t >> 6;
    const float* aSrc = Ab + min(m0 + am, NFD - 1);     // clamp; masked at C-write
    const int awb = am * 80 + ao * 16;
    // B: 512 units = 128 n x 4 octets: thread t covers (n=t&127, o=bo0) and (n, bo1)
    const int bn0 = t & 127;
    const int bo0 = (t >> 7) & 3;            // t<128 -> 0, t>=128 -> 1
    const int bo1 = ((256 + t) >> 7) & 3;    // t<128 -> 2, t>=128 -> 3
    const float* bSrc0 = Bb + min(bn0, KD - 1);
    const int bwb0 = bn0 * 80 + bo0 * 16;
    const int bwb1 = bn0 * 80 + bo1 * 16;

    // ---- wave geometry: 4 waves 2x2, wave tile 32(m) x 64(n) ----
    const int lane = t & 63;
    const int wid  = t >> 6;
    const int wm = wid >> 1, wn = wid & 1;
    const int r16 = lane & 15;
    const int g   = lane >> 4;

    int aoffs[2], boffs[4];
    #pragma unroll
    for (int mf = 0; mf < 2; ++mf)
        aoffs[mf] = (wm * 32 + mf * 16 + r16) * 80 + g * 16;
    #pragma unroll
    for (int nf = 0; nf < 4; ++nf)
        boffs[nf] = 10240 + (wn * 64 + nf * 16 + r16) * 80 + g * 16;

    float4v acc[2][4];
    #pragma unroll
    for (int mf = 0; mf < 2; ++mf)
        #pragma unroll
        for (int nf = 0; nf < 4; ++nf)
            acc[mf][nf] = float4v{0.f, 0.f, 0.f, 0.f};

    const int chv0 = ch * 1024;
    const int nst  = (ch < 4) ? 32 : 29;     // ch4: 29*32=928 covers 904 valid v

    float a8[8], b8a[8], b8b[8];             // staging registers

    auto load_regs = [&](int st) {
        const int v0 = chv0 + st * 32;
        const int va  = v0 + ao * 8;
        const int vb0 = v0 + bo0 * 8;
        const int vb1 = v0 + bo1 * 8;
        if (v0 + 32 <= VV) {
            #pragma unroll
            for (int j = 0; j < 8; ++j) a8[j]  = aSrc [(size_t)(va  + j) * NFD];
            #pragma unroll
            for (int j = 0; j < 8; ++j) b8a[j] = bSrc0[(size_t)(vb0 + j) * KD];
            #pragma unroll
            for (int j = 0; j < 8; ++j) b8b[j] = bSrc0[(size_t)(vb1 + j) * KD];
        } else {
            #pragma unroll
            for (int j = 0; j < 8; ++j) {
                float v = 0.f;
                if (va + j < VV) v = aSrc[(size_t)(va + j) * NFD];
                a8[j] = v;
            }
            #pragma unroll
            for (int j = 0; j < 8; ++j) {
                float v = 0.f;
                if (vb0 + j < VV) v = bSrc0[(size_t)(vb0 + j) * KD];
                b8a[j] = v;
            }
            #pragma unroll
            for (int j = 0; j < 8; ++j) {
                float v = 0.f;
                if (vb1 + j < VV) v = bSrc0[(size_t)(vb1 + j) * KD];
                b8b[j] = v;
            }
        }
    };

    auto pack_write = [&]() {
        int4 hi, lo;
        pack8(a8, hi, lo);
        *(int4*)(lds + awb)          = hi;   // A_hi plane @0
        *(int4*)(lds + 5120 + awb)   = lo;   // A_lo plane @5120
        pack8(b8a, hi, lo);
        *(int4*)(lds + 10240 + bwb0) = hi;   // B_hi plane @10240
        *(int4*)(lds + 20480 + bwb0) = lo;   // B_lo plane @20480
        pack8(b8b, hi, lo);
        *(int4*)(lds + 10240 + bwb1) = hi;
        *(int4*)(lds + 20480 + bwb1) = lo;
    };

    auto frag_mfma = [&]() {
        short8 ah[2], al[2];
        #pragma unroll
        for (int mf = 0; mf < 2; ++mf) {
            ah[mf] = *(const short8*)(lds + aoffs[mf]);
            al[mf] = *(const short8*)(lds + 5120 + aoffs[mf]);
        }
        #pragma unroll
        for (int nf = 0; nf < 4; ++nf) {
            const short8 bh = *(const short8*)(lds + boffs[nf]);            // B_hi
            const short8 bl = *(const short8*)(lds + 10240 + boffs[nf]);    // B_lo (boffs incl. 10240)
            #pragma unroll
            for (int mf = 0; mf < 2; ++mf) {
                acc[mf][nf] = __builtin_amdgcn_mfma_f32_16x16x32_bf16(ah[mf], bh, acc[mf][nf], 0, 0, 0);
                acc[mf][nf] = __builtin_amdgcn_mfma_f32_16x16x32_bf16(ah[mf], bl, acc[mf][nf], 0, 0, 0);
                acc[mf][nf] = __builtin_amdgcn_mfma_f32_16x16x32_bf16(al[mf], bh, acc[mf][nf], 0, 0, 0);
            }
        }
    };

    // ---- prologue ----
    load_regs(0);
    pack_write();
    __syncthreads();

    // ---- main loop: issue loads early, write late (T14) ----
    for (int st = 0; st < nst; ++st) {
        if (st + 1 < nst) load_regs(st + 1);   // HBM latency hides under MFMA
        frag_mfma();
        __syncthreads();                       // all frag reads done
        if (st + 1 < nst) {
            pack_write();                      // publish st+1
            __syncthreads();
        }
    }

    // ---- store partial C tile: slab[m*120 + n] ----
    float* slab = partials + (size_t)((ch * 2 + wh) * NB + b) * SLABSZ;
    #pragma unroll
    for (int mf = 0; mf < 2; ++mf) {
        const int mrow = mt * 64 + wm * 32 + mf * 16 + g * 4;
        #pragma unroll
        for (int nf = 0; nf < 4; ++nf) {
            const int n = wn * 64 + nf * 16 + r16;
            if (n < KD) {
                #pragma unroll
                for (int r = 0; r < 4; ++r) {
                    const int m = mrow + r;
                    if (m < NFD) slab[(size_t)m * KD + n] = acc[mf][nf][r];
                }
            }
        }
    }
}

// ---------------------------------------------------------------------------
// reduce (unchanged)
// ---------------------------------------------------------------------------
__global__ __launch_bounds__(256) void reduce_k(
    const float* __restrict__ partials, float* __restrict__ fhat, float* __restrict__ ghat)
{
    const int id = blockIdx.x * 256 + threadIdx.x;
    if (id >= NFD * KD) return;
    const int wb = blockIdx.y;
    const int wh = wb >> 4;
    const int b  = wb & 15;

    const float* p = partials + (size_t)(wh * NB + b) * SLABSZ + id;
    const size_t chstride = (size_t)2 * NB * SLABSZ;

    float s = 0.f;
    #pragma unroll
    for (int c = 0; c < NCH; ++c) s += p[c * chstride];

    float* dst = (wh ? ghat : fhat) + (size_t)b * NFD * KD + id;
    *dst = s;
}

// ---------------------------------------------------------------------------
// Generic TN SGEMM 64x64 tile — used by gram (unchanged, passing).
// ---------------------------------------------------------------------------
__device__ __forceinline__ void gemm_tn_64x64(
    const float* __restrict__ A, const float* __restrict__ B, float* __restrict__ C,
    int V, int M, int N, int m0, int n0)
{
    __shared__ float As[16][64];
    __shared__ float Bs[16][64];

    const int tid = threadIdx.x;
    const int tx = tid & 15;
    const int ty = tid >> 4;
    const int sr = tid >> 4;
    const int sc = (tid & 15) << 2;

    float acc[4][4] = {{0.f,0.f,0.f,0.f},{0.f,0.f,0.f,0.f},
                       {0.f,0.f,0.f,0.f},{0.f,0.f,0.f,0.f}};

    for (int v0 = 0; v0 < V; v0 += 16) {
        const int v = v0 + sr;
        float4 av; av.x = av.y = av.z = av.w = 0.f;
        float4 bv; bv.x = bv.y = bv.z = bv.w = 0.f;
        if (v < V) {
            const float* Ar = A + (size_t)v * M;
            const int ca = m0 + sc;
            if (ca + 3 < M) {
                av = *(const float4*)(Ar + ca);
            } else {
                if (ca + 0 < M) av.x = Ar[ca + 0];
                if (ca + 1 < M) av.y = Ar[ca + 1];
                if (ca + 2 < M) av.z = Ar[ca + 2];
                if (ca + 3 < M) av.w = Ar[ca + 3];
            }
            const float* Br = B + (size_t)v * N;
            const int cb = n0 + sc;
            if (cb + 3 < N) {
                bv = *(const float4*)(Br + cb);
            } else {
                if (cb + 0 < N) bv.x = Br[cb + 0];
                if (cb + 1 < N) bv.y = Br[cb + 1];
                if (cb + 2 < N) bv.z = Br[cb + 2];
                if (cb + 3 < N) bv.w = Br[cb + 3];
            }
        }
        __syncthreads();
        *(float4*)&As[sr][sc] = av;
        *(float4*)&Bs[sr][sc] = bv;
        __syncthreads();

        #pragma unroll
        for (int kk = 0; kk < 16; ++kk) {
            const float4 a4 = *(const float4*)&As[kk][ty << 2];
            const float4 b4 = *(const float4*)&Bs[kk][tx << 2];
            const float a[4]  = {a4.x, a4.y, a4.z, a4.w};
            const float bb[4] = {b4.x, b4.y, b4.z, b4.w};
            #pragma unroll
            for (int i = 0; i < 4; ++i)
                #pragma unroll
                for (int j = 0; j < 4; ++j)
                    acc[i][j] = fmaf(a[i], bb[j], acc[i][j]);
        }
    }

    #pragma unroll
    for (int i = 0; i < 4; ++i) {
        const int m = m0 + (ty << 2) + i;
        if (m < M) {
            #pragma unroll
            for (int j = 0; j < 4; ++j) {
                const int n = n0 + (tx << 2) + j;
                if (n < N) C[(size_t)m * N + n] = acc[i][j];
            }
        }
    }
}

__global__ __launch_bounds__(256) void gram_kernel(
    const float* __restrict__ fhat, const float* __restrict__ ghat,
    float* __restrict__ ftf, float* __restrict__ gtg, float* __restrict__ ftg)
{
    const int b = blockIdx.z;
    const int which = blockIdx.y;
    const int m0 = (blockIdx.x & 1) * 64;
    const int n0 = (blockIdx.x >> 1) * 64;

    const float* F = fhat + (size_t)b * NFD * KD;
    const float* G = ghat + (size_t)b * NFD * KD;
    const float* A  = (which == 1) ? G : F;
    const float* Bp = (which == 0) ? F : G;
    float* C = ((which == 0) ? ftf : (which == 1) ? gtg : ftg) + (size_t)b * KD * KD;

    gemm_tn_64x64(A, Bp, C, NFD, KD, KD, m0, n0);
}

// ---------------------------------------------------------------------------
// solve v6 (unchanged, passing): 480-thread Gauss-Jordan, 60 named scalars,
// padded 20-float prow segments (bank-clean), R=4 row reuse.
// ---------------------------------------------------------------------------
__device__ __forceinline__ float ldval(const float* __restrict__ A, const float* __restrict__ B,
                                       int pair, int row, int col) {
    if (col < KD) return A[row * KD + col];
    const int l = col - KD;
    return pair ? B[l * KD + row] : B[row * KD + l];
}

#define FOR15(OP) OP(0) OP(1) OP(2) OP(3) OP(4) OP(5) OP(6) OP(7) OP(8) OP(9) \
                  OP(10) OP(11) OP(12) OP(13) OP(14)

__global__ __launch_bounds__(480, 1) void solve_kernel(
    const float* __restrict__ ftf, const float* __restrict__ gtg,
    const float* __restrict__ ftg, float* __restrict__ out)
{
    const int pair = blockIdx.x;
    const int b = blockIdx.y;
    const int tid = threadIdx.x;
    const int cg = tid & 15;
    const int rg = tid >> 4;
    const int cbase = cg * 15;
    const int r0 = rg * 4;
    const int seg = cg * 20;

    const float* Ag = ((pair == 0) ? ftf : gtg) + (size_t)b * KD * KD;
    const float* Bg = ftg + (size_t)b * KD * KD;

    __shared__ __align__(16) float prow[2][320];
    __shared__ __align__(16) float pcol[2][120];

    #define DECL(I) float w##I = ldval(Ag, Bg, pair, r0 + 0, cbase + (I)); \
                    float x##I = ldval(Ag, Bg, pair, r0 + 1, cbase + (I)); \
                    float y##I = ldval(Ag, Bg, pair, r0 + 2, cbase + (I)); \
                    float z##I = ldval(Ag, Bg, pair, r0 + 3, cbase + (I));
    FOR15(DECL)
    #undef DECL

    if (rg == 0) {
        #define PUB0(I) prow[0][seg + (I)] = w##I;
        FOR15(PUB0)
        #undef PUB0
    }
    if (cg == 0) *(float4*)&pcol[0][r0] = float4{w0, x0, y0, z0};
    __syncthreads();

    int jseg = 0, joff = 0;

    for (int j = 0; j < KD; ++j) {
        const int cur = j & 1;
        const int nxt = cur ^ 1;

        const float pinv = 1.0f / prow[cur][jseg * 20 + joff];
        const float4 f4 = *(const float4*)&pcol[cur][r0];

        const float4 q0 = *(const float4*)&prow[cur][seg + 0];
        const float4 q1 = *(const float4*)&prow[cur][seg + 4];
        const float4 q2 = *(const float4*)&prow[cur][seg + 8];
        const float4 q3 = *(const float4*)&prow[cur][seg + 12];
        const float p0 = q0.x, p1 = q0.y, p2 = q0.z, p3 = q0.w;
        const float p4 = q1.x, p5 = q1.y, p6 = q1.z, p7 = q1.w;
        const float p8 = q2.x, p9 = q2.y, p10 = q2.z, p11 = q2.w;
        const float p12 = q3.x, p13 = q3.y, p14 = q3.z;

        const float fw = f4.x * pinv, fx = f4.y * pinv;
        const float fy = f4.z * pinv, fz = f4.w * pinv;

        #define UPD(I) w##I = fmaf(-fw, p##I, w##I); x##I = fmaf(-fx, p##I, x##I); \
                       y##I = fmaf(-fy, p##I, y##I); z##I = fmaf(-fz, p##I, z##I);
        FOR15(UPD)
        #undef UPD

        if (rg == (j >> 2)) {
            #define FW(I) w##I = p##I * pinv;
            #define FX(I) x##I = p##I * pinv;
            #define FY(I) y##I = p##I * pinv;
            #define FZ(I) z##I = p##I * pinv;
            switch (j & 3) {
                case 0: FOR15(FW) break;
                case 1: FOR15(FX) break;
                case 2: FOR15(FY) break;
                default: FOR15(FZ) break;
            }
            #undef FW
            #undef FX
            #undef FY
            #undef FZ
        }

        const int j2 = j + 1;

        if (j2 < KD && rg == (j2 >> 2)) {
            #define PW(I) prow[nxt][seg + (I)] = w##I;
            #define PX(I) prow[nxt][seg + (I)] = x##I;
            #define PY(I) prow[nxt][seg + (I)] = y##I;
            #define PZ(I) prow[nxt][seg + (I)] = z##I;
            switch (j2 & 3) {
                case 0: FOR15(PW) break;
                case 1: FOR15(PX) break;
                case 2: FOR15(PY) break;
                default: FOR15(PZ) break;
            }
            #undef PW
            #undef PX
            #undef PY
            #undef PZ
        }

        joff++; if (joff == 15) { joff = 0; jseg++; }
        if (j2 < KD && cg == jseg) {
            #define PC(I) case I: *(float4*)&pcol[nxt][r0] = float4{w##I, x##I, y##I, z##I}; break;
            switch (joff) {
                FOR15(PC)
                default: break;
            }
            #undef PC
        }
        __syncthreads();
    }

    if (cg >= 8) {
        float* op = out + (size_t)pair * NB * KD * KD + (size_t)b * KD * KD;
        #define OUTW(I) { const int l = cbase + (I) - KD; \
                          *(float4*)&op[l * KD + r0] = float4{w##I, x##I, y##I, z##I}; }
        FOR15(OUTW)
        #undef OUTW
    }
}

// ---------------------------------------------------------------------------
extern "C" void kernel_launch(void* const* d_in, const int* in_sizes, int n_in,
                              void* d_out, int out_size, void* d_ws, size_t ws_size,
                              hipStream_t stream)
{
    const float* feat_x  = (const float*)d_in[0];
    const float* feat_y  = (const float*)d_in[1];
    const float* evecs_x = (const float*)d_in[2];
    const float* evecs_y = (const float*)d_in[3];
    float* out = (float*)d_out;

    // ws layout (floats): pad 64 | partials 6,758,400 | fhat/ghat 675,840 ea.
    // ftf/gtg/ftg alias the partials region (dead after reduce_k).
    float* ws       = (float*)d_ws;
    float* partials = ws + 64;
    float* fhat     = partials + (size_t)NCH * 2 * NB * SLABSZ;
    float* ghat     = fhat + (size_t)NB * NFD * KD;
    float* ftf      = ws + 64;                            // aliases partials
    float* gtg      = ftf + (size_t)NB * KD * KD;
    float* ftg      = gtg + (size_t)NB * KD * KD;

    proj_mfma <<<dim3(30, 2, NB), 256, 0, stream>>>(feat_x, feat_y, evecs_x, evecs_y, partials);
    reduce_k  <<<dim3(165, 32), 256, 0, stream>>>(partials, fhat, ghat);
    gram_kernel<<<dim3(4, 3, NB), 256, 0, stream>>>(fhat, ghat, ftf, gtg, ftg);
    solve_kernel<<<dim3(2, NB), 480, 0, stream>>>(ftf, gtg, ftg, out);
}